// Round 7
// baseline (182.857 us; speedup 1.0000x reference)
//
#include <hip/hip_runtime.h>

#define Bn 4
#define Tn 512
#define Mn 16
#define Dn 128
#define Pn 128
#define Hn 4
#define SCALE 0.08838834764831845f  // 1 / (2*sqrt(32))

#define N4_INP (Bn * Tn * Mn * Dn / 4)   // 1048576 float4
#define N4_POS (Bn * Tn * Dn / 4)        // 65536
#define N4_W   (Mn * Pn * Dn / 4)        // 65536 per weight array
#define WSZ    (Mn * Pn * Dn)            // 262144 elems per weight array
#define CVT_BLOCKS ((N4_INP + N4_POS + 5 * N4_W) / 256)  // 5632

typedef unsigned short u16;
typedef unsigned int u32;
typedef short s16;
typedef __attribute__((ext_vector_type(8))) s16 bf16x8;   // 8 bf16 = 4 VGPRs
typedef __attribute__((ext_vector_type(4))) float f32x4;  // MFMA C/D

__device__ __forceinline__ u16 f2b(float f) {  // fp32 -> bf16 rne
  u32 x; __builtin_memcpy(&x, &f, 4);
  x += 0x7fffu + ((x >> 16) & 1u);
  return (u16)(x >> 16);
}
__device__ __forceinline__ u32 pack2(float a, float b) {
  return (u32)f2b(a) | ((u32)f2b(b) << 16);
}
__device__ __forceinline__ bf16x8 ld8(const u16* p) {  // 16B frag load
  bf16x8 r; __builtin_memcpy(&r, p, 16); return r;
}
__device__ __forceinline__ f32x4 mfma16(bf16x8 a, bf16x8 b, f32x4 c) {
  // Verified mapping (rounds 2-4): D row (quad*4+reg) = a's l16-index,
  // D col (lane&15) = b's l16-index, k = kc*32 + quad*8 in both gathers.
  return __builtin_amdgcn_mfma_f32_16x16x32_bf16(a, b, c, 0, 0, 0);
}
#define ZERO4 ((f32x4){0.f, 0.f, 0.f, 0.f})

// ---------------------------------------------------------------- lengths ---
// Round-4 verbatim. mask[b,t,m] = (t < len[b]); len[b] = #nonzero mask[b,:,0].
__global__ void lengths_kernel(const void* __restrict__ mask, int* __restrict__ len_out) {
  const int b = blockIdx.x;
  __shared__ int cnt[256];
  const u32 w0 = ((const u32*)mask)[0];
  const int mode = (w0 == 1u) ? 0 : (w0 == 0x3F800000u) ? 1
                 : (w0 == 0x3F803F80u) ? 2 : 3;
  int c = 0;
  for (int t = threadIdx.x; t < Tn; t += 256) {
    const size_t idx = ((size_t)b * Tn + t) * Mn;
    int nz;
    if (mode == 0)      nz = (((const int*)mask)[idx] != 0);
    else if (mode == 1) nz = (((const u32*)mask)[idx] != 0u);
    else if (mode == 2) nz = (((const u16*)mask)[idx] != 0);
    else                nz = (((const unsigned char*)mask)[idx] != 0);
    c += nz;
  }
  cnt[threadIdx.x] = c;
  __syncthreads();
  for (int s = 128; s > 0; s >>= 1) {
    if (threadIdx.x < (unsigned)s) cnt[threadIdx.x] += cnt[threadIdx.x + s];
    __syncthreads();
  }
  if (threadIdx.x == 0) len_out[b] = cnt[0];
}

// ------------------------------------------------------------------- cvt ----
// PURE convert: fp32 -> bf16 of inp/pos/W; last block copies biases to ws.
__global__ __launch_bounds__(256) void cvt_kernel(
    const float* __restrict__ inp, const float* __restrict__ pos,
    const float* __restrict__ Wq, const float* __restrict__ Wk,
    const float* __restrict__ Wv, const float* __restrict__ Wqt,
    const float* __restrict__ Wkt,
    const float* __restrict__ Bq, const float* __restrict__ Bk,
    const float* __restrict__ Bv, const float* __restrict__ Bqt,
    const float* __restrict__ Bkt,
    u16* __restrict__ Xbf, u16* __restrict__ Pbf, u16* __restrict__ Wbf,
    float* __restrict__ Bws) {
  const int gb = blockIdx.x;
  if (gb < CVT_BLOCKS) {
    const int i = gb * 256 + threadIdx.x;  // float4 index
    const float* src; u16* dst; int off;
    if (i < N4_INP) {
      src = inp; dst = Xbf; off = i;
    } else if (i < N4_INP + N4_POS) {
      src = pos; dst = Pbf; off = i - N4_INP;
    } else {
      const int w = i - (N4_INP + N4_POS);
      const int tsel = w >> 16;            // 65536 float4 per W array
      off = w & 65535;
      dst = Wbf + tsel * WSZ;
      src = (tsel == 0) ? Wq : (tsel == 1) ? Wk : (tsel == 2) ? Wv
          : (tsel == 3) ? Wqt : Wkt;
    }
    const float4 v = ((const float4*)src)[off];
    ushort4 o;
    o.x = f2b(v.x); o.y = f2b(v.y); o.z = f2b(v.z); o.w = f2b(v.w);
    ((ushort4*)dst)[off] = o;
  } else {
    for (int i = threadIdx.x; i < 5 * Mn * Pn; i += 256) {
      const int arr = i >> 11, idx = i & 2047;   // Mn*Pn = 2048
      const float* src = (arr == 0) ? Bq : (arr == 1) ? Bk : (arr == 2) ? Bv
                       : (arr == 3) ? Bqt : Bkt;
      Bws[i] = src[idx];
    }
  }
}

// --------------------------------------------------------- projection v3 ----
// Wave-autonomous, no LDS, no barriers; round-4 proven MFMA orientation.
// BUGFIX vs rounds 5/6: store-time row index is bt0 & (Tn-1), NOT global bt0
// (global bt0 scattered batches b>=1 into wrong bmh slots -> absmax 5.72).
__global__ __launch_bounds__(256, 2) void proj_mfma(
    const u16* __restrict__ Xbf, const u16* __restrict__ Pbf,
    const u16* __restrict__ Wbf, const float* __restrict__ Bws,
    u16* __restrict__ Qa, u16* __restrict__ Ka, u16* __restrict__ Qb,
    u16* __restrict__ Kb, u16* __restrict__ Vt) {
  const int tid = threadIdx.x;
  const int wv = tid >> 6, lane = tid & 63;
  const int quad = lane >> 4, l16 = lane & 15;
  const int wu = blockIdx.x * 4 + wv;      // 0..2047

  const int isqkv = (wu < 1024);
  const int wu2 = isqkv ? wu : wu - 1024;
  const int rg = wu2 & 63;                 // 32-row group (never crosses b)
  const int m = wu2 >> 6;
  const int bt0 = rg * 32;                 // global row (for READS)
  const int tl = bt0 & (Tn - 1);           // local-t base (for STORES)  [FIX]
  const int b = bt0 >> 9;
  const int bmh0 = (b * Mn + m) * Hn;

  if (isqkv) {
    const u16* Wqp = Wbf + 0 * WSZ + m * Pn * Dn;
    const u16* Wkp = Wbf + 1 * WSZ + m * Pn * Dn;
    const u16* Wvp = Wbf + 2 * WSZ + m * Pn * Dn;
    f32x4 accQ[2][8], accK[2][8], accV[2][8];
#pragma unroll
    for (int tt = 0; tt < 2; ++tt)
#pragma unroll
      for (int n = 0; n < 8; ++n) {
        accQ[tt][n] = ZERO4; accK[tt][n] = ZERO4; accV[tt][n] = ZERO4;
      }
#pragma unroll
    for (int kc = 0; kc < 4; ++kc) {
      const int ko = kc * 32 + quad * 8;
      const bf16x8 x0 = ld8(Xbf + ((size_t)(bt0 + l16) * Mn + m) * Dn + ko);
      const bf16x8 x1 = ld8(Xbf + ((size_t)(bt0 + 16 + l16) * Mn + m) * Dn + ko);
#pragma unroll
      for (int n = 0; n < 8; ++n) {
        const size_t wr = (size_t)(n * 16 + l16) * Dn + ko;
        const bf16x8 wq = ld8(Wqp + wr);
        const bf16x8 wk = ld8(Wkp + wr);
        const bf16x8 wvv = ld8(Wvp + wr);
        accQ[0][n] = mfma16(x0, wq, accQ[0][n]);
        accQ[1][n] = mfma16(x1, wq, accQ[1][n]);
        accK[0][n] = mfma16(x0, wk, accK[0][n]);
        accK[1][n] = mfma16(x1, wk, accK[1][n]);
        accV[0][n] = mfma16(x0, wvv, accV[0][n]);
        accV[1][n] = mfma16(x1, wvv, accV[1][n]);
      }
    }
#pragma unroll
    for (int n = 0; n < 8; ++n) {
      const int p = n * 16 + l16;
      const int h = p >> 5, e = p & 31;
      const int bmh = bmh0 + h;
      const float bq = Bws[0 * 2048 + m * Pn + p];
      const float bk = Bws[1 * 2048 + m * Pn + p];
      const float bv = Bws[2 * 2048 + m * Pn + p];
#pragma unroll
      for (int tt = 0; tt < 2; ++tt) {
#pragma unroll
        for (int reg = 0; reg < 4; ++reg) {
          const int t = tl + tt * 16 + quad * 4 + reg;                 // [FIX]
          const size_t ad = ((size_t)bmh * Tn + t) * 32 + e;
          Qa[ad] = f2b((accQ[tt][n][reg] + bq) * SCALE);
          Ka[ad] = f2b(accK[tt][n][reg] + bk);
        }
        const int t0 = tl + tt * 16 + quad * 4;                        // [FIX]
        uint2 dv;
        dv.x = pack2(accV[tt][n][0] + bv, accV[tt][n][1] + bv);
        dv.y = pack2(accV[tt][n][2] + bv, accV[tt][n][3] + bv);
        *(uint2*)&Vt[((size_t)bmh * 32 + e) * Tn + t0] = dv;
      }
    }
  } else {
    const u16* Wqp = Wbf + 3 * WSZ + m * Pn * Dn;   // Wq_t
    const u16* Wkp = Wbf + 4 * WSZ + m * Pn * Dn;   // Wk_t
    f32x4 accQ[2][8], accK[2][8];
#pragma unroll
    for (int tt = 0; tt < 2; ++tt)
#pragma unroll
      for (int n = 0; n < 8; ++n) { accQ[tt][n] = ZERO4; accK[tt][n] = ZERO4; }
#pragma unroll
    for (int kc = 0; kc < 4; ++kc) {
      const int ko = kc * 32 + quad * 8;
      const bf16x8 x0 = ld8(Pbf + (size_t)(bt0 + l16) * Dn + ko);
      const bf16x8 x1 = ld8(Pbf + (size_t)(bt0 + 16 + l16) * Dn + ko);
#pragma unroll
      for (int n = 0; n < 8; ++n) {
        const size_t wr = (size_t)(n * 16 + l16) * Dn + ko;
        const bf16x8 wq = ld8(Wqp + wr);
        const bf16x8 wk = ld8(Wkp + wr);
        accQ[0][n] = mfma16(x0, wq, accQ[0][n]);
        accQ[1][n] = mfma16(x1, wq, accQ[1][n]);
        accK[0][n] = mfma16(x0, wk, accK[0][n]);
        accK[1][n] = mfma16(x1, wk, accK[1][n]);
      }
    }
#pragma unroll
    for (int n = 0; n < 8; ++n) {
      const int p = n * 16 + l16;
      const int h = p >> 5, e = p & 31;
      const int bmh = bmh0 + h;
      const float bq = Bws[3 * 2048 + m * Pn + p];
      const float bk = Bws[4 * 2048 + m * Pn + p];
#pragma unroll
      for (int tt = 0; tt < 2; ++tt)
#pragma unroll
        for (int reg = 0; reg < 4; ++reg) {
          const int t = tl + tt * 16 + quad * 4 + reg;                 // [FIX]
          const size_t ad = ((size_t)bmh * Tn + t) * 32 + e;
          Qb[ad] = f2b((accQ[tt][n][reg] + bq) * SCALE);
          Kb[ad] = f2b(accK[tt][n][reg] + bk);
        }
    }
  }
}

// ------------------------------------------------------- attention (flash) ---
// Round-4 verbatim (passing).
__global__ __launch_bounds__(256, 4) void attn_flash(
    const u16* __restrict__ Qa, const u16* __restrict__ Ka,
    const u16* __restrict__ Qb, const u16* __restrict__ Kb,
    const u16* __restrict__ Vt, const int* __restrict__ lens,
    float* __restrict__ out) {
  __shared__ __align__(16) u16 Ps[4 * 32 * 72];  // 18.4KB, per-wave slabs

  const int tid = threadIdx.x;
  const int wv = tid >> 6, lane = tid & 63;
  const int quad = lane >> 4, l16 = lane & 15;

  const int wu = blockIdx.x * 4 + wv;      // 0..4095
  const int qt = wu & 15;
  const int bmh = wu >> 4;
  const int b = bmh >> 6;                  // Mn*Hn = 64
  const int len = lens[b];
  const int q0 = qt * 32;

  const size_t rowbase = (size_t)bmh * Tn;
  const size_t vbase = (size_t)bmh * 32 * Tn;
  u16* myPs = &Ps[wv * 32 * 72];

  bf16x8 qf[2][2];
#pragma unroll
  for (int qs = 0; qs < 2; ++qs) {
    const size_t r = (rowbase + q0 + qs * 16 + l16) * 32 + quad * 8;
    qf[qs][0] = ld8(Qa + r);
    qf[qs][1] = ld8(Qb + r);
  }

  f32x4 O[2][2];  // [qs][es], D rows = e (quad*4+reg), cols = q (l16)
#pragma unroll
  for (int qs = 0; qs < 2; ++qs)
#pragma unroll
    for (int es = 0; es < 2; ++es) O[qs][es] = ZERO4;
  float mrow[2] = {-1e30f, -1e30f}, lsum[2] = {0.f, 0.f};

  const int s_hi = min(q0 + 32, len);      // len >= T/2 >= 1
  for (int s0 = 0; s0 < s_hi; s0 += 64) {
    f32x4 S[2][4];
#pragma unroll
    for (int st = 0; st < 4; ++st) {
      const size_t kr = (rowbase + s0 + st * 16 + l16) * 32 + quad * 8;
      const bf16x8 k0 = ld8(Ka + kr);
      const bf16x8 k1 = ld8(Kb + kr);
#pragma unroll
      for (int qs = 0; qs < 2; ++qs)
        S[qs][st] = mfma16(k1, qf[qs][1], mfma16(k0, qf[qs][0], ZERO4));
    }

#pragma unroll
    for (int qs = 0; qs < 2; ++qs) {
      const int q = q0 + qs * 16 + l16;
      const int qcap = min(q, len - 1);    // valid <=> s <= qcap
      const int sb = s0 + quad * 4;
      float cmax = -1e30f;
#pragma unroll
      for (int st = 0; st < 4; ++st)
#pragma unroll
        for (int reg = 0; reg < 4; ++reg) {
          const int s = sb + st * 16 + reg;
          const float v = (s <= qcap) ? S[qs][st][reg] : -1e30f;
          S[qs][st][reg] = v;
          cmax = fmaxf(cmax, v);
        }
      cmax = fmaxf(cmax, __shfl_xor(cmax, 16));
      cmax = fmaxf(cmax, __shfl_xor(cmax, 32));
      const float mnew = fmaxf(mrow[qs], cmax);   // finite: >=1 valid key/chunk
      const float alpha = __expf(mrow[qs] - mnew);
      mrow[qs] = mnew;
      float rsum = 0.f;
      u32 pk[4][2];
#pragma unroll
      for (int st = 0; st < 4; ++st) {
        const float p0 = __expf(S[qs][st][0] - mnew);
        const float p1 = __expf(S[qs][st][1] - mnew);
        const float p2 = __expf(S[qs][st][2] - mnew);
        const float p3 = __expf(S[qs][st][3] - mnew);
        rsum += (p0 + p1) + (p2 + p3);
        pk[st][0] = pack2(p0, p1);
        pk[st][1] = pack2(p2, p3);
      }
      rsum += __shfl_xor(rsum, 16);
      rsum += __shfl_xor(rsum, 32);
      lsum[qs] = lsum[qs] * alpha + rsum;
#pragma unroll
      for (int es = 0; es < 2; ++es)
#pragma unroll
        for (int reg = 0; reg < 4; ++reg) O[qs][es][reg] *= alpha;
#pragma unroll
      for (int st = 0; st < 4; ++st) {
        uint2 d; d.x = pk[st][0]; d.y = pk[st][1];
        *(uint2*)&myPs[(qs * 16 + l16) * 72 + st * 16 + quad * 4] = d;
      }
    }

    // O^T += V^T . P
#pragma unroll
    for (int kc = 0; kc < 2; ++kc) {
      const int ko = kc * 32 + quad * 8;
      const bf16x8 pf0 = ld8(&myPs[l16 * 72 + ko]);
      const bf16x8 pf1 = ld8(&myPs[(16 + l16) * 72 + ko]);
      const bf16x8 vf0 = ld8(Vt + vbase + (size_t)l16 * Tn + s0 + ko);
      const bf16x8 vf1 = ld8(Vt + vbase + (size_t)(16 + l16) * Tn + s0 + ko);
      O[0][0] = mfma16(vf0, pf0, O[0][0]);
      O[0][1] = mfma16(vf1, pf0, O[0][1]);
      O[1][0] = mfma16(vf0, pf1, O[1][0]);
      O[1][1] = mfma16(vf1, pf1, O[1][1]);
    }
  }

  const int mm = (bmh >> 2) & (Mn - 1);
  const int h = bmh & (Hn - 1);
#pragma unroll
  for (int qs = 0; qs < 2; ++qs) {
    const float linv = 1.0f / lsum[qs];
    const int t = q0 + qs * 16 + l16;
    const size_t ob = (((size_t)b * Tn + t) * Mn + mm) * Pn + h * 32 + quad * 4;
#pragma unroll
    for (int es = 0; es < 2; ++es) {
      float4 o;
      o.x = O[qs][es][0] * linv; o.y = O[qs][es][1] * linv;
      o.z = O[qs][es][2] * linv; o.w = O[qs][es][3] * linv;
      *(float4*)&out[ob + es * 16] = o;
    }
  }
}

// ------------------------------------------------------------------ launch ---
extern "C" void kernel_launch(void* const* d_in, const int* in_sizes, int n_in,
                              void* d_out, int out_size, void* d_ws, size_t ws_size,
                              hipStream_t stream) {
  const float* inp = (const float*)d_in[0];
  const float* pos = (const float*)d_in[1];
  const void* mask = d_in[2];
  const float* Wq  = (const float*)d_in[3];
  const float* Bq  = (const float*)d_in[4];
  const float* Wk  = (const float*)d_in[5];
  const float* Bk  = (const float*)d_in[6];
  const float* Wv  = (const float*)d_in[7];
  const float* Bv  = (const float*)d_in[8];
  const float* Wqt = (const float*)d_in[9];
  const float* Bqt = (const float*)d_in[10];
  const float* Wkt = (const float*)d_in[11];
  const float* Bkt = (const float*)d_in[12];
  float* out = (float*)d_out;

  const size_t nA = (size_t)Bn * Mn * Hn * Tn * 32;  // 4.19M elems per array
  u16* Qa = (u16*)d_ws;
  u16* Ka = Qa + nA;
  u16* Qb = Ka + nA;
  u16* Kb = Qb + nA;
  u16* Vt = Kb + nA;
  u16* Xbf = Vt + nA;                                 // B*T*M*D bf16
  u16* Pbf = Xbf + (size_t)Bn * Tn * Mn * Dn;         // B*T*D
  u16* Wbf = Pbf + (size_t)Bn * Tn * Dn;              // 5*WSZ
  float* Bws = (float*)(Wbf + 5 * (size_t)WSZ);       // 5*2048 fp32
  int* lens = (int*)(Bws + 5 * 2048);

  lengths_kernel<<<Bn, 256, 0, stream>>>(mask, lens);
  cvt_kernel<<<CVT_BLOCKS + 1, 256, 0, stream>>>(
      inp, pos, Wq, Wk, Wv, Wqt, Wkt, Bq, Bk, Bv, Bqt, Bkt,
      Xbf, Pbf, Wbf, Bws);
  proj_mfma<<<2048 / 4, 256, 0, stream>>>(Xbf, Pbf, Wbf, Bws, Qa, Ka, Qb, Kb, Vt);
  attn_flash<<<Bn * Mn * Hn * (Tn / 32) / 4, 256, 0, stream>>>(
      Qa, Ka, Qb, Kb, Vt, lens, out);
}

// Round 8
// 163.769 us; speedup vs baseline: 1.1165x; 1.1165x over previous
//
#include <hip/hip_runtime.h>

#define Bn 4
#define Tn 512
#define Mn 16
#define Dn 128
#define Pn 128
#define Hn 4
#define SCALE 0.08838834764831845f  // 1 / (2*sqrt(32))

#define N4_INP (Bn * Tn * Mn * Dn / 4)   // 1048576 float4
#define N4_POS (Bn * Tn * Dn / 4)        // 65536
#define N4_W   (Mn * Pn * Dn / 4)        // 65536 per weight array
#define WSZ    (Mn * Pn * Dn)            // 262144 elems per weight array
#define CVT_BLOCKS ((N4_INP + N4_POS + 5 * N4_W) / 256)  // 5632

typedef unsigned short u16;
typedef unsigned int u32;
typedef short s16;
typedef __attribute__((ext_vector_type(8))) s16 bf16x8;   // 8 bf16 = 4 VGPRs
typedef __attribute__((ext_vector_type(4))) float f32x4;  // MFMA C/D

__device__ __forceinline__ u16 f2b(float f) {  // fp32 -> bf16 rne
  u32 x; __builtin_memcpy(&x, &f, 4);
  x += 0x7fffu + ((x >> 16) & 1u);
  return (u16)(x >> 16);
}
__device__ __forceinline__ u32 pack2(float a, float b) {
  return (u32)f2b(a) | ((u32)f2b(b) << 16);
}
__device__ __forceinline__ bf16x8 ld8(const u16* p) {  // 16B frag load
  bf16x8 r; __builtin_memcpy(&r, p, 16); return r;
}
__device__ __forceinline__ void st8(u16* p, bf16x8 v) {  // 16B store
  __builtin_memcpy(p, &v, 16);
}
__device__ __forceinline__ f32x4 mfma16(bf16x8 a, bf16x8 b, f32x4 c) {
  // Verified mapping (rounds 2-4,7): D row (quad*4+reg) = a's l16-index,
  // D col (lane&15) = b's l16-index, k = kc*32 + quad*8 in both gathers.
  return __builtin_amdgcn_mfma_f32_16x16x32_bf16(a, b, c, 0, 0, 0);
}
#define ZERO4 ((f32x4){0.f, 0.f, 0.f, 0.f})

// ------------------------------------------------------------------- cvt ----
// Blocks [0,CVT_BLOCKS): fp32->bf16 of inp/pos/W. Block CVT_BLOCKS: biases to
// fp32 ws. Block CVT_BLOCKS+1: lengths from mask (probed encoding; elem 0 is
// always true since len >= T/2). Lengths-in-cvt proven equivalent (r5 vs r6:
// identical absmax with folded vs standalone).
__global__ __launch_bounds__(256) void cvt_kernel(
    const float* __restrict__ inp, const float* __restrict__ pos,
    const float* __restrict__ Wq, const float* __restrict__ Wk,
    const float* __restrict__ Wv, const float* __restrict__ Wqt,
    const float* __restrict__ Wkt,
    const float* __restrict__ Bq, const float* __restrict__ Bk,
    const float* __restrict__ Bv, const float* __restrict__ Bqt,
    const float* __restrict__ Bkt, const void* __restrict__ mask,
    u16* __restrict__ Xbf, u16* __restrict__ Pbf, u16* __restrict__ Wbf,
    float* __restrict__ Bws, int* __restrict__ lens) {
  const int gb = blockIdx.x;
  if (gb < CVT_BLOCKS) {
    const int i = gb * 256 + threadIdx.x;  // float4 index
    const float* src; u16* dst; int off;
    if (i < N4_INP) {
      src = inp; dst = Xbf; off = i;
    } else if (i < N4_INP + N4_POS) {
      src = pos; dst = Pbf; off = i - N4_INP;
    } else {
      const int w = i - (N4_INP + N4_POS);
      const int tsel = w >> 16;            // 65536 float4 per W array
      off = w & 65535;
      dst = Wbf + tsel * WSZ;
      src = (tsel == 0) ? Wq : (tsel == 1) ? Wk : (tsel == 2) ? Wv
          : (tsel == 3) ? Wqt : Wkt;
    }
    const float4 v = ((const float4*)src)[off];
    ushort4 o;
    o.x = f2b(v.x); o.y = f2b(v.y); o.z = f2b(v.z); o.w = f2b(v.w);
    ((ushort4*)dst)[off] = o;
  } else if (gb == CVT_BLOCKS) {
    for (int i = threadIdx.x; i < 5 * Mn * Pn; i += 256) {
      const int arr = i >> 11, idx = i & 2047;   // Mn*Pn = 2048
      const float* src = (arr == 0) ? Bq : (arr == 1) ? Bk : (arr == 2) ? Bv
                       : (arr == 3) ? Bqt : Bkt;
      Bws[i] = src[idx];
    }
  } else {
    // lengths: wave w handles batch w (Bn=4 waves used)
    const int b = threadIdx.x >> 6, lane = threadIdx.x & 63;
    const u32 w0 = ((const u32*)mask)[0];
    const int mode = (w0 == 1u) ? 0 : (w0 == 0x3F800000u) ? 1
                   : (w0 == 0x3F803F80u) ? 2 : 3;
    int c = 0;
    for (int t = lane; t < Tn; t += 64) {
      const size_t idx = ((size_t)b * Tn + t) * Mn;
      int nz;
      if (mode == 0)      nz = (((const int*)mask)[idx] != 0);
      else if (mode == 1) nz = (((const u32*)mask)[idx] != 0u);
      else if (mode == 2) nz = (((const u16*)mask)[idx] != 0);
      else                nz = (((const unsigned char*)mask)[idx] != 0);
      c += nz;
    }
    for (int o = 32; o; o >>= 1) c += __shfl_xor(c, o);
    if (lane == 0) lens[b] = c;
  }
}

// --------------------------------------------------------- projection v4 ----
// Wave-autonomous, no barriers. Wave = (tsel, m, 32-row group); 5120 waves in
// 1280 blocks (5 blocks/CU). Loads: coalesced 16B frag loads from cvt's bf16
// arrays (weights L2-resident). Stores: D-tiles round-trip through a PRIVATE
// per-wave LDS slab (stride-40 rows: 16B-aligned readback, quad-split banks),
// then 16B/lane global stores with 4 lanes covering each 64B line exactly —
// fixes round-7's 2.3x write amplification (97 MB vs 42 MB of data).
__global__ __launch_bounds__(256, 2) void proj_mfma(
    const u16* __restrict__ Xbf, const u16* __restrict__ Pbf,
    const u16* __restrict__ Wbf, const float* __restrict__ Bws,
    u16* __restrict__ Qa, u16* __restrict__ Ka, u16* __restrict__ Qb,
    u16* __restrict__ Kb, u16* __restrict__ Vt) {
  __shared__ __align__(16) u16 slab_all[4][4][32][40];  // 40 KB: [wave][np][row][40]

  const int tid = threadIdx.x;
  const int wv = tid >> 6, lane = tid & 63;
  const int quad = lane >> 4, l16 = lane & 15;
  const int wu = blockIdx.x * 4 + wv;      // 0..5119

  const int tsel = wu % 5;
  const int rest = wu / 5;                 // 0..1023
  const int m = rest & (Mn - 1);
  const int rg = rest >> 4;                // 0..63 (32-row group; never crosses b)
  const int bt0 = rg * 32;                 // global row (READS)
  const int tl = bt0 & (Tn - 1);           // local-t base (STORES)
  const int b = bt0 >> 9;
  const int bmh0 = (b * Mn + m) * Hn;
  u16 (*slab)[32][40] = slab_all[wv];

  const u16* W = Wbf + tsel * WSZ + m * Pn * Dn;
  const float* bias = Bws + tsel * 2048 + m * Pn;
  const int usepos = (tsel >= 3);

  f32x4 acc[2][8];
#pragma unroll
  for (int tt = 0; tt < 2; ++tt)
#pragma unroll
    for (int n = 0; n < 8; ++n) acc[tt][n] = ZERO4;

#pragma unroll
  for (int kc = 0; kc < 4; ++kc) {
    const int ko = kc * 32 + quad * 8;
    bf16x8 x0, x1;
    if (usepos) {
      x0 = ld8(Pbf + (size_t)(bt0 + l16) * Dn + ko);
      x1 = ld8(Pbf + (size_t)(bt0 + 16 + l16) * Dn + ko);
    } else {
      x0 = ld8(Xbf + ((size_t)(bt0 + l16) * Mn + m) * Dn + ko);
      x1 = ld8(Xbf + ((size_t)(bt0 + 16 + l16) * Mn + m) * Dn + ko);
    }
#pragma unroll
    for (int n = 0; n < 8; ++n) {
      const bf16x8 w = ld8(W + (size_t)(n * 16 + l16) * Dn + ko);
      acc[0][n] = mfma16(x0, w, acc[0][n]);
      acc[1][n] = mfma16(x1, w, acc[1][n]);
    }
  }

  if (tsel == 2) {
    // V: transposed tiles [e][t] -> Vt[bmh][e][t], packed 8B ds writes
#pragma unroll
    for (int n = 0; n < 8; ++n) {
      const int np = n >> 1;               // = h
      const int e_loc = (n & 1) * 16 + l16;
      const float bv = bias[n * 16 + l16];
#pragma unroll
      for (int tt = 0; tt < 2; ++tt) {
        const int t_loc = tt * 16 + quad * 4;
        uint2 d;
        d.x = pack2(acc[tt][n][0] + bv, acc[tt][n][1] + bv);
        d.y = pack2(acc[tt][n][2] + bv, acc[tt][n][3] + bv);
        *(uint2*)&slab[np][e_loc][t_loc] = d;
      }
    }
#pragma unroll
    for (int np = 0; np < 4; ++np)
#pragma unroll
      for (int i = 0; i < 2; ++i) {
        const int c = i * 64 + lane;
        const int e_loc = c >> 2, sub = c & 3;   // 4 lanes per 64B line
        const bf16x8 v = ld8(&slab[np][e_loc][sub * 8]);
        st8(Vt + ((size_t)(bmh0 + np) * 32 + e_loc) * Tn + tl + sub * 8, v);
      }
  } else {
    u16* dst = (tsel == 0) ? Qa : (tsel == 1) ? Ka : (tsel == 3) ? Qb : Kb;
    const float sc = (tsel == 0 || tsel == 3) ? SCALE : 1.f;
    // Q/K: [t][e] tiles -> dst[bmh][t][32]
#pragma unroll
    for (int n = 0; n < 8; ++n) {
      const int np = n >> 1;               // = h
      const int e = (n & 1) * 16 + l16;
      const float bv = bias[n * 16 + l16];
#pragma unroll
      for (int tt = 0; tt < 2; ++tt)
#pragma unroll
        for (int reg = 0; reg < 4; ++reg) {
          const int t_loc = tt * 16 + quad * 4 + reg;
          slab[np][t_loc][e] = f2b((acc[tt][n][reg] + bv) * sc);
        }
    }
#pragma unroll
    for (int np = 0; np < 4; ++np)
#pragma unroll
      for (int i = 0; i < 2; ++i) {
        const int c = i * 64 + lane;
        const int t_loc = c >> 2, sub = c & 3;   // 4 lanes per 64B line
        const bf16x8 v = ld8(&slab[np][t_loc][sub * 8]);
        st8(dst + ((size_t)(bmh0 + np) * Tn + tl + t_loc) * 32 + sub * 8, v);
      }
  }
}

// ------------------------------------------------------- attention (flash) ---
// Round-4/7 verbatim (passing). Wave = 32 q-rows of one (b,m,h); S^T = K.Q^T;
// fp32 online softmax (xor16/32 shuffles); P via private per-wave LDS slab
// (no __syncthreads); O^T = V^T.P; coalesced float4 epilogue.
__global__ __launch_bounds__(256, 4) void attn_flash(
    const u16* __restrict__ Qa, const u16* __restrict__ Ka,
    const u16* __restrict__ Qb, const u16* __restrict__ Kb,
    const u16* __restrict__ Vt, const int* __restrict__ lens,
    float* __restrict__ out) {
  __shared__ __align__(16) u16 Ps[4 * 32 * 72];  // 18.4KB, per-wave slabs

  const int tid = threadIdx.x;
  const int wv = tid >> 6, lane = tid & 63;
  const int quad = lane >> 4, l16 = lane & 15;

  const int wu = blockIdx.x * 4 + wv;      // 0..4095
  const int qt = wu & 15;
  const int bmh = wu >> 4;
  const int b = bmh >> 6;                  // Mn*Hn = 64
  const int len = lens[b];
  const int q0 = qt * 32;

  const size_t rowbase = (size_t)bmh * Tn;
  const size_t vbase = (size_t)bmh * 32 * Tn;
  u16* myPs = &Ps[wv * 32 * 72];

  bf16x8 qf[2][2];
#pragma unroll
  for (int qs = 0; qs < 2; ++qs) {
    const size_t r = (rowbase + q0 + qs * 16 + l16) * 32 + quad * 8;
    qf[qs][0] = ld8(Qa + r);
    qf[qs][1] = ld8(Qb + r);
  }

  f32x4 O[2][2];  // [qs][es], D rows = e (quad*4+reg), cols = q (l16)
#pragma unroll
  for (int qs = 0; qs < 2; ++qs)
#pragma unroll
    for (int es = 0; es < 2; ++es) O[qs][es] = ZERO4;
  float mrow[2] = {-1e30f, -1e30f}, lsum[2] = {0.f, 0.f};

  const int s_hi = min(q0 + 32, len);      // len >= T/2 >= 1
  for (int s0 = 0; s0 < s_hi; s0 += 64) {
    f32x4 S[2][4];
#pragma unroll
    for (int st = 0; st < 4; ++st) {
      const size_t kr = (rowbase + s0 + st * 16 + l16) * 32 + quad * 8;
      const bf16x8 k0 = ld8(Ka + kr);
      const bf16x8 k1 = ld8(Kb + kr);
#pragma unroll
      for (int qs = 0; qs < 2; ++qs)
        S[qs][st] = mfma16(k1, qf[qs][1], mfma16(k0, qf[qs][0], ZERO4));
    }

#pragma unroll
    for (int qs = 0; qs < 2; ++qs) {
      const int q = q0 + qs * 16 + l16;
      const int qcap = min(q, len - 1);    // valid <=> s <= qcap
      const int sb = s0 + quad * 4;
      float cmax = -1e30f;
#pragma unroll
      for (int st = 0; st < 4; ++st)
#pragma unroll
        for (int reg = 0; reg < 4; ++reg) {
          const int s = sb + st * 16 + reg;
          const float v = (s <= qcap) ? S[qs][st][reg] : -1e30f;
          S[qs][st][reg] = v;
          cmax = fmaxf(cmax, v);
        }
      cmax = fmaxf(cmax, __shfl_xor(cmax, 16));
      cmax = fmaxf(cmax, __shfl_xor(cmax, 32));
      const float mnew = fmaxf(mrow[qs], cmax);   // finite: >=1 valid key/chunk
      const float alpha = __expf(mrow[qs] - mnew);
      mrow[qs] = mnew;
      float rsum = 0.f;
      u32 pk[4][2];
#pragma unroll
      for (int st = 0; st < 4; ++st) {
        const float p0 = __expf(S[qs][st][0] - mnew);
        const float p1 = __expf(S[qs][st][1] - mnew);
        const float p2 = __expf(S[qs][st][2] - mnew);
        const float p3 = __expf(S[qs][st][3] - mnew);
        rsum += (p0 + p1) + (p2 + p3);
        pk[st][0] = pack2(p0, p1);
        pk[st][1] = pack2(p2, p3);
      }
      rsum += __shfl_xor(rsum, 16);
      rsum += __shfl_xor(rsum, 32);
      lsum[qs] = lsum[qs] * alpha + rsum;
#pragma unroll
      for (int es = 0; es < 2; ++es)
#pragma unroll
        for (int reg = 0; reg < 4; ++reg) O[qs][es][reg] *= alpha;
#pragma unroll
      for (int st = 0; st < 4; ++st) {
        uint2 d; d.x = pk[st][0]; d.y = pk[st][1];
        *(uint2*)&myPs[(qs * 16 + l16) * 72 + st * 16 + quad * 4] = d;
      }
    }

    // O^T += V^T . P
#pragma unroll
    for (int kc = 0; kc < 2; ++kc) {
      const int ko = kc * 32 + quad * 8;
      const bf16x8 pf0 = ld8(&myPs[l16 * 72 + ko]);
      const bf16x8 pf1 = ld8(&myPs[(16 + l16) * 72 + ko]);
      const bf16x8 vf0 = ld8(Vt + vbase + (size_t)l16 * Tn + s0 + ko);
      const bf16x8 vf1 = ld8(Vt + vbase + (size_t)(16 + l16) * Tn + s0 + ko);
      O[0][0] = mfma16(vf0, pf0, O[0][0]);
      O[0][1] = mfma16(vf1, pf0, O[0][1]);
      O[1][0] = mfma16(vf0, pf1, O[1][0]);
      O[1][1] = mfma16(vf1, pf1, O[1][1]);
    }
  }

  const int mm = (bmh >> 2) & (Mn - 1);
  const int h = bmh & (Hn - 1);
#pragma unroll
  for (int qs = 0; qs < 2; ++qs) {
    const float linv = 1.0f / lsum[qs];
    const int t = q0 + qs * 16 + l16;
    const size_t ob = (((size_t)b * Tn + t) * Mn + mm) * Pn + h * 32 + quad * 4;
#pragma unroll
    for (int es = 0; es < 2; ++es) {
      float4 o;
      o.x = O[qs][es][0] * linv; o.y = O[qs][es][1] * linv;
      o.z = O[qs][es][2] * linv; o.w = O[qs][es][3] * linv;
      *(float4*)&out[ob + es * 16] = o;
    }
  }
}

// ------------------------------------------------------------------ launch ---
extern "C" void kernel_launch(void* const* d_in, const int* in_sizes, int n_in,
                              void* d_out, int out_size, void* d_ws, size_t ws_size,
                              hipStream_t stream) {
  const float* inp = (const float*)d_in[0];
  const float* pos = (const float*)d_in[1];
  const void* mask = d_in[2];
  const float* Wq  = (const float*)d_in[3];
  const float* Bq  = (const float*)d_in[4];
  const float* Wk  = (const float*)d_in[5];
  const float* Bk  = (const float*)d_in[6];
  const float* Wv  = (const float*)d_in[7];
  const float* Bv  = (const float*)d_in[8];
  const float* Wqt = (const float*)d_in[9];
  const float* Bqt = (const float*)d_in[10];
  const float* Wkt = (const float*)d_in[11];
  const float* Bkt = (const float*)d_in[12];
  float* out = (float*)d_out;

  const size_t nA = (size_t)Bn * Mn * Hn * Tn * 32;  // 4.19M elems per array
  u16* Qa = (u16*)d_ws;
  u16* Ka = Qa + nA;
  u16* Qb = Ka + nA;
  u16* Kb = Qb + nA;
  u16* Vt = Kb + nA;
  u16* Xbf = Vt + nA;                                 // B*T*M*D bf16
  u16* Pbf = Xbf + (size_t)Bn * Tn * Mn * Dn;         // B*T*D
  u16* Wbf = Pbf + (size_t)Bn * Tn * Dn;              // 5*WSZ
  float* Bws = (float*)(Wbf + 5 * (size_t)WSZ);       // 5*2048 fp32
  int* lens = (int*)(Bws + 5 * 2048);

  cvt_kernel<<<CVT_BLOCKS + 2, 256, 0, stream>>>(
      inp, pos, Wq, Wk, Wv, Wqt, Wkt, Bq, Bk, Bv, Bqt, Bkt, mask,
      Xbf, Pbf, Wbf, Bws, lens);
  proj_mfma<<<5120 / 4, 256, 0, stream>>>(Xbf, Pbf, Wbf, Bws, Qa, Ka, Qb, Kb, Vt);
  attn_flash<<<Bn * Mn * Hn * (Tn / 32) / 4, 256, 0, stream>>>(
      Qa, Ka, Qb, Kb, Vt, lens, out);
}